// Round 1
// baseline (347.942 us; speedup 1.0000x reference)
//
#include <hip/hip_runtime.h>
#include <hip/hip_bf16.h>
#include <cstdint>
#include <cstddef>

typedef __bf16 bf16;
typedef __attribute__((ext_vector_type(8))) __bf16 bf16x8;
typedef __attribute__((ext_vector_type(4))) float f32x4;

#define DEVINL __device__ __forceinline__

DEVINL void gload16(const void* g, void* l) {
  __builtin_amdgcn_global_load_lds(
      (const __attribute__((address_space(1))) void*)g,
      (__attribute__((address_space(3))) void*)l, 16, 0, 0);
}

DEVINL f32x4 mfma16(bf16x8 a, bf16x8 b, f32x4 c) {
  return __builtin_amdgcn_mfma_f32_16x16x32_bf16(a, b, c, 0, 0, 0);
}

// ---------------- cast x fp32 -> bf16, 8 elem/thread ----------------
__global__ __launch_bounds__(256) void cast_x_kernel(const float* __restrict__ x,
                                                     bf16* __restrict__ o, int n8) {
  int i = blockIdx.x * 256 + threadIdx.x;
  if (i >= n8) return;
  f32x4 a = ((const f32x4*)x)[2 * i];
  f32x4 b = ((const f32x4*)x)[2 * i + 1];
  bf16x8 v;
#pragma unroll
  for (int k = 0; k < 4; ++k) { v[k] = (bf16)a[k]; v[4 + k] = (bf16)b[k]; }
  ((bf16x8*)o)[i] = v;
}

// ---------- transpose+cast: src fp32 [K][N] -> dst bf16 [N][K] (K stride 2048) ----------
__global__ __launch_bounds__(256) void transpose_cast_kernel(const float* __restrict__ src,
                                                             bf16* __restrict__ dst,
                                                             int K, int N) {
  __shared__ float tile[64][65];
  int nt = N >> 6;
  int n0 = (blockIdx.x % nt) << 6;
  int k0 = (blockIdx.x / nt) << 6;
  int c = threadIdx.x & 63, rb = threadIdx.x >> 6;
#pragma unroll
  for (int rr = 0; rr < 16; ++rr) {
    int row = rr * 4 + rb;
    tile[row][c] = src[(size_t)(k0 + row) * N + n0 + c];
  }
  __syncthreads();
#pragma unroll
  for (int rr = 0; rr < 16; ++rr) {
    int nrow = rr * 4 + rb;
    dst[(size_t)(n0 + nrow) * K + k0 + c] = (bf16)tile[c][nrow];
  }
}

// ---------------- GEMM: C[M][N] = A[M][2048] * BT[N][2048]^T  (m97 structure) ----------------
// 128x128 tile, 4 waves (2x2), BK=32, global_load_lds width 16.
// EPI 0: scatter QKV epilogue (bf16 to Qbuf/Kbuf/VTbuf); EPI 1: fp32 C.
template <int EPI>
__global__ __launch_bounds__(256) void gemm_bt_kernel(const bf16* __restrict__ A,
                                                      const bf16* __restrict__ BT,
                                                      float* __restrict__ Cout,
                                                      int Mtiles,
                                                      bf16* __restrict__ qb,
                                                      bf16* __restrict__ kb_,
                                                      bf16* __restrict__ vtb) {
  __shared__ __align__(16) unsigned char smem[16384];  // A: [0,8192) B: [8192,16384)
  const int t = threadIdx.x, w = t >> 6, lane = t & 63;
  const int l4 = lane >> 4, l16 = lane & 15;
  const int bm = blockIdx.x % Mtiles, bn = blockIdx.x / Mtiles;
  const int wm = w >> 1, wn = w & 1;

  const char* aP[2];
  const char* bP[2];
#pragma unroll
  for (int p = 0; p < 2; ++p) {
    int g = p * 256 + t;
    aP[p] = (const char*)A + (size_t)(bm * 128 + (g >> 2)) * 4096 + (g & 3) * 16;
    bP[p] = (const char*)BT + (size_t)(bn * 128 + (g >> 2)) * 4096 + (g & 3) * 16;
  }
  const unsigned ldsW = w * 1024;

  const f32x4 fz = {0.f, 0.f, 0.f, 0.f};
  f32x4 acc[4][4];
#pragma unroll
  for (int i = 0; i < 4; ++i)
#pragma unroll
    for (int j = 0; j < 4; ++j) acc[i][j] = fz;

  const int arow = 64 * wm + l16, brow = 64 * wn + l16, kbyte = 16 * l4;

#pragma unroll 2
  for (int k0 = 0; k0 < 4096; k0 += 64) {  // byte offset along K (32 bf16 per step)
    gload16(aP[0] + k0, smem + ldsW);
    gload16(aP[1] + k0, smem + 4096 + ldsW);
    gload16(bP[0] + k0, smem + 8192 + ldsW);
    gload16(bP[1] + k0, smem + 12288 + ldsW);
    __syncthreads();
    bf16x8 af[4], bfr[4];
#pragma unroll
    for (int i = 0; i < 4; ++i)
      af[i] = *(const bf16x8*)(smem + (arow + 16 * i) * 64 + kbyte);
#pragma unroll
    for (int j = 0; j < 4; ++j)
      bfr[j] = *(const bf16x8*)(smem + 8192 + (brow + 16 * j) * 64 + kbyte);
#pragma unroll
    for (int i = 0; i < 4; ++i)
#pragma unroll
      for (int j = 0; j < 4; ++j)
        acc[i][j] = mfma16(af[i], bfr[j], acc[i][j]);
    __syncthreads();
  }

  const int r0 = bm * 128 + 64 * wm + 4 * l4;
  if (EPI == 1) {
#pragma unroll
    for (int j = 0; j < 4; ++j) {
      int col = bn * 128 + 64 * wn + 16 * j + l16;
#pragma unroll
      for (int i = 0; i < 4; ++i)
#pragma unroll
        for (int r = 0; r < 4; ++r)
          Cout[(size_t)(r0 + 16 * i + r) * 2048 + col] = acc[i][j][r];
    }
  } else {
    const int bq = bm >> 4;  // batch (rows [bm*128, +128) never cross the 2048 boundary)
#pragma unroll
    for (int j = 0; j < 4; ++j) {
      int col = bn * 128 + 64 * wn + 16 * j + l16;
      if (bn < 16) {        // Q -> [b][h][n][d]
        int hh = col >> 7, d = col & 127;
        bf16* dst = qb + (size_t)((bq * 16 + hh) * 2048) * 128 + d;
#pragma unroll
        for (int i = 0; i < 4; ++i)
#pragma unroll
          for (int r = 0; r < 4; ++r) {
            int n = (r0 + 16 * i + r) & 2047;
            dst[(size_t)n * 128] = (bf16)acc[i][j][r];
          }
      } else if (bn < 20) { // K -> [b][kv][n][d]
        int kv = (col >> 7) - 16, d = col & 127;
        bf16* dst = kb_ + (size_t)((bq * 4 + kv) * 2048) * 128 + d;
#pragma unroll
        for (int i = 0; i < 4; ++i)
#pragma unroll
          for (int r = 0; r < 4; ++r) {
            int n = (r0 + 16 * i + r) & 2047;
            dst[(size_t)n * 128] = (bf16)acc[i][j][r];
          }
      } else {              // V -> transposed [b][kv][d][n]
        int kv = (col >> 7) - 20, d = col & 127;
        bf16* dst = vtb + ((size_t)(bq * 4 + kv) * 128 + d) * 2048;
#pragma unroll
        for (int i = 0; i < 4; ++i)
#pragma unroll
          for (int r = 0; r < 4; ++r) {
            int n = (r0 + 16 * i + r) & 2047;
            dst[n] = (bf16)acc[i][j][r];
          }
      }
    }
  }
}

// ---------------- flash attention (GQA), 4 waves x 32 q-rows, KVBLK=64 ----------------
// LDS: K tile [64][128] @0 (swizzled), VT tile [128][64] @16384 (swizzled),
//      per-wave P [32][64] @32768 + w*4096 (swizzled). All swizzles: byte ^= (row&7)<<4.
__global__ __launch_bounds__(256) void attn_kernel(const bf16* __restrict__ Q,
                                                   const bf16* __restrict__ K,
                                                   const bf16* __restrict__ VT,
                                                   bf16* __restrict__ AO) {
  __shared__ __align__(16) unsigned char smem[49152];
  const int t = threadIdx.x, w = t >> 6, lane = t & 63;
  const int l4 = lane >> 4, l16 = lane & 15;
  const int pair = blockIdx.x >> 4;
  const int q00 = (blockIdx.x & 15) * 128 + w * 32;
  const int b = pair >> 4, h = pair & 15, kv = h >> 2;
  const float KS2 = 0.08838834764831845f * 1.4426950408889634f;  // scale * log2(e)

  // Q fragments resident in registers (2 qt x 4 d-chunks)
  bf16x8 qf[2][4];
  {
    const char* qbase = (const char*)Q +
        ((size_t)((b * 16 + h) * 2048 + q00 + l16) * 128 + 8 * l4) * 2;
#pragma unroll
    for (int qt = 0; qt < 2; ++qt)
#pragma unroll
      for (int c = 0; c < 4; ++c)
        qf[qt][c] = *(const bf16x8*)(qbase + qt * 16 * 256 + c * 64);
  }

  const f32x4 fz = {0.f, 0.f, 0.f, 0.f};
  f32x4 acc[2][8];
  float mrun[2][4], lrun[2][4];
#pragma unroll
  for (int qt = 0; qt < 2; ++qt) {
#pragma unroll
    for (int dc = 0; dc < 8; ++dc) acc[qt][dc] = fz;
#pragma unroll
    for (int r = 0; r < 4; ++r) { mrun[qt][r] = -1e30f; lrun[qt][r] = 0.0f; }
  }

  const char* Kg = (const char*)K + (size_t)((b * 4 + kv) * 2048) * 256;
  const char* Vg = (const char*)VT + (size_t)((b * 4 + kv) * 128) * 4096;
  const unsigned pbase = 32768 + w * 4096;

#pragma unroll 1
  for (int it = 0; it < 32; ++it) {
    const int kb = it * 64;
    // stage K tile (pre-swizzled global source -> linear LDS dest)
#pragma unroll
    for (int p = 0; p < 4; ++p) {
      int g = p * 256 + t;
      int row = g >> 4, cb = (g & 15) * 16;
      gload16(Kg + (size_t)(kb + row) * 256 + (cb ^ ((row & 7) << 4)),
              smem + p * 4096 + w * 1024);
    }
    // stage VT tile
#pragma unroll
    for (int p = 0; p < 4; ++p) {
      int g = p * 256 + t;
      int row = g >> 3, cb = (g & 7) * 16;
      gload16(Vg + (size_t)row * 4096 + kb * 2 + (cb ^ ((row & 7) << 4)),
              smem + 16384 + p * 4096 + w * 1024);
    }
    __syncthreads();

    // S = Q K^T   (raw scores; scale folded into exp2)
    f32x4 s[2][4];
#pragma unroll
    for (int qt = 0; qt < 2; ++qt)
#pragma unroll
      for (int kt = 0; kt < 4; ++kt) s[qt][kt] = fz;
#pragma unroll
    for (int c = 0; c < 4; ++c)
#pragma unroll
      for (int kt = 0; kt < 4; ++kt) {
        int key = kt * 16 + l16;
        bf16x8 bk = *(const bf16x8*)(smem + key * 256 +
                                     ((64 * c + 16 * l4) ^ ((key & 7) << 4)));
        s[0][kt] = mfma16(qf[0][c], bk, s[0][kt]);
        s[1][kt] = mfma16(qf[1][c], bk, s[1][kt]);
      }

    // online softmax per q-row (rows 4*l4+r), wave-parallel reduce over 16 lanes
#pragma unroll
    for (int qt = 0; qt < 2; ++qt)
#pragma unroll
      for (int r = 0; r < 4; ++r) {
        float v = fmaxf(fmaxf(s[qt][0][r], s[qt][1][r]),
                        fmaxf(s[qt][2][r], s[qt][3][r]));
        v = fmaxf(v, __shfl_xor(v, 1, 64));
        v = fmaxf(v, __shfl_xor(v, 2, 64));
        v = fmaxf(v, __shfl_xor(v, 4, 64));
        v = fmaxf(v, __shfl_xor(v, 8, 64));
        float mn = fmaxf(mrun[qt][r], v);
        float al = exp2f(KS2 * (mrun[qt][r] - mn));
        mrun[qt][r] = mn;
        int prow = qt * 16 + 4 * l4 + r;
        unsigned pb = pbase + prow * 128;
        unsigned sw = (prow & 7) << 4;
        float rs = 0.0f;
#pragma unroll
        for (int kt = 0; kt < 4; ++kt) {
          float p = exp2f(KS2 * (s[qt][kt][r] - mn));
          rs += p;
          *(bf16*)(smem + pb + (((kt * 16 + l16) * 2) ^ sw)) = (bf16)p;
        }
        rs += __shfl_xor(rs, 1, 64);
        rs += __shfl_xor(rs, 2, 64);
        rs += __shfl_xor(rs, 4, 64);
        rs += __shfl_xor(rs, 8, 64);
        lrun[qt][r] = lrun[qt][r] * al + rs;
#pragma unroll
        for (int dc = 0; dc < 8; ++dc) acc[qt][dc][r] *= al;
      }

    // O += P * V
#pragma unroll
    for (int kc = 0; kc < 2; ++kc) {
      bf16x8 pa[2];
#pragma unroll
      for (int qt = 0; qt < 2; ++qt) {
        int row = qt * 16 + l16;
        pa[qt] = *(const bf16x8*)(smem + pbase + row * 128 +
                                  ((kc * 64 + 16 * l4) ^ ((row & 7) << 4)));
      }
#pragma unroll
      for (int dc = 0; dc < 8; ++dc) {
        int d = dc * 16 + l16;
        bf16x8 bv = *(const bf16x8*)(smem + 16384 + d * 128 +
                                     ((kc * 64 + 16 * l4) ^ ((d & 7) << 4)));
        acc[0][dc] = mfma16(pa[0], bv, acc[0][dc]);
        acc[1][dc] = mfma16(pa[1], bv, acc[1][dc]);
      }
    }
    __syncthreads();
  }

  // epilogue: normalize, store bf16 AO[b*2048+q][h*128+d]
#pragma unroll
  for (int qt = 0; qt < 2; ++qt) {
    float inv[4];
#pragma unroll
    for (int r = 0; r < 4; ++r) inv[r] = 1.0f / lrun[qt][r];
#pragma unroll
    for (int dc = 0; dc < 8; ++dc)
#pragma unroll
      for (int r = 0; r < 4; ++r) {
        int qrow = q00 + qt * 16 + 4 * l4 + r;
        int col = h * 128 + dc * 16 + l16;
        AO[(size_t)(b * 2048 + qrow) * 2048 + col] = (bf16)(acc[qt][dc][r] * inv[r]);
      }
  }
}

extern "C" void kernel_launch(void* const* d_in, const int* in_sizes, int n_in,
                              void* d_out, int out_size, void* d_ws, size_t ws_size,
                              hipStream_t stream) {
  const float* x = (const float*)d_in[0];
  const float* Wq = (const float*)d_in[1];
  const float* Wk = (const float*)d_in[2];
  const float* Wv = (const float*)d_in[3];
  const float* Wo = (const float*)d_in[4];

  char* ws = (char*)d_ws;
  bf16* xbf = (bf16*)(ws);                  // 16 MiB  [4096][2048]; reused as AO after QKV GEMM
  bf16* WqkvT = (bf16*)(ws + 16777216);     // 12 MiB  [3072][2048]
  bf16* WoT = (bf16*)(ws + 29360128);       //  8 MiB  [2048][2048]
  bf16* Qbuf = (bf16*)(ws + 37748736);      // 16 MiB  [b][h][n][128]
  bf16* Kbuf = (bf16*)(ws + 54525952);      //  4 MiB  [b][kv][n][128]
  bf16* VTbuf = (bf16*)(ws + 58720256);     //  4 MiB  [b][kv][128][n]   (end: 60 MiB)

  cast_x_kernel<<<4096, 256, 0, stream>>>(x, xbf, 1048576);
  transpose_cast_kernel<<<1024, 256, 0, stream>>>(Wq, WqkvT, 2048, 2048);
  transpose_cast_kernel<<<256, 256, 0, stream>>>(Wk, WqkvT + (size_t)2048 * 2048, 2048, 512);
  transpose_cast_kernel<<<256, 256, 0, stream>>>(Wv, WqkvT + (size_t)2560 * 2048, 2048, 512);
  transpose_cast_kernel<<<1024, 256, 0, stream>>>(Wo, WoT, 2048, 2048);

  gemm_bt_kernel<0><<<768, 256, 0, stream>>>(xbf, WqkvT, nullptr, 32, Qbuf, Kbuf, VTbuf);
  attn_kernel<<<512, 256, 0, stream>>>(Qbuf, Kbuf, VTbuf, xbf /* -> AO, reuses xbf */);
  gemm_bt_kernel<1><<<512, 256, 0, stream>>>(xbf, WoT, (float*)d_out, 32, nullptr, nullptr, nullptr);
}

// Round 3
// 216.469 us; speedup vs baseline: 1.6074x; 1.6074x over previous
//
#include <hip/hip_runtime.h>
#include <hip/hip_bf16.h>
#include <cstdint>
#include <cstddef>

typedef __bf16 bf16;
typedef __attribute__((ext_vector_type(8))) __bf16 bf16x8;
typedef __attribute__((ext_vector_type(4))) float f32x4;
typedef __attribute__((ext_vector_type(16))) float f32x16;
typedef unsigned int u32;
typedef __attribute__((ext_vector_type(2))) unsigned int u32x2;

#define DEVINL __device__ __forceinline__

DEVINL void gload16(const void* g, void* l) {
  __builtin_amdgcn_global_load_lds(
      (const __attribute__((address_space(1))) void*)g,
      (__attribute__((address_space(3))) void*)l, 16, 0, 0);
}

DEVINL f32x4 mfma16(bf16x8 a, bf16x8 b, f32x4 c) {
  return __builtin_amdgcn_mfma_f32_16x16x32_bf16(a, b, c, 0, 0, 0);
}
DEVINL f32x16 mfma32(bf16x8 a, bf16x8 b, f32x16 c) {
  return __builtin_amdgcn_mfma_f32_32x32x16_bf16(a, b, c, 0, 0, 0);
}
DEVINL u32 cvtpk(float lo, float hi) {
  u32 r;
  asm("v_cvt_pk_bf16_f32 %0, %1, %2" : "=v"(r) : "v"(lo), "v"(hi));
  return r;
}
DEVINL void plswap(u32& a, u32& b) {
  asm("v_permlane32_swap_b32 %0, %1" : "+v"(a), "+v"(b));
}

// ---------------- cast x fp32 -> bf16, 8 elem/thread ----------------
__global__ __launch_bounds__(256) void cast_x_kernel(const float* __restrict__ x,
                                                     bf16* __restrict__ o, int n8) {
  int i = blockIdx.x * 256 + threadIdx.x;
  if (i >= n8) return;
  f32x4 a = ((const f32x4*)x)[2 * i];
  f32x4 b = ((const f32x4*)x)[2 * i + 1];
  bf16x8 v;
#pragma unroll
  for (int k = 0; k < 4; ++k) { v[k] = (bf16)a[k]; v[4 + k] = (bf16)b[k]; }
  ((bf16x8*)o)[i] = v;
}

// ---------- transpose+cast: src fp32 [K][N] -> dst bf16 [N][K] (K stride 2048) ----------
__global__ __launch_bounds__(256) void transpose_cast_kernel(const float* __restrict__ src,
                                                             bf16* __restrict__ dst,
                                                             int K, int N) {
  __shared__ float tile[64][65];
  int nt = N >> 6;
  int n0 = (blockIdx.x % nt) << 6;
  int k0 = (blockIdx.x / nt) << 6;
  int c = threadIdx.x & 63, rb = threadIdx.x >> 6;
#pragma unroll
  for (int rr = 0; rr < 16; ++rr) {
    int row = rr * 4 + rb;
    tile[row][c] = src[(size_t)(k0 + row) * N + n0 + c];
  }
  __syncthreads();
#pragma unroll
  for (int rr = 0; rr < 16; ++rr) {
    int nrow = rr * 4 + rb;
    dst[(size_t)(n0 + nrow) * K + k0 + c] = (bf16)tile[c][nrow];
  }
}

// ---------------- GEMM: C[M][N] = A[M][2048] * BT[N][2048]^T  (m97 structure) ----------------
template <int EPI>
__global__ __launch_bounds__(256) void gemm_bt_kernel(const bf16* __restrict__ A,
                                                      const bf16* __restrict__ BT,
                                                      float* __restrict__ Cout,
                                                      int Mtiles,
                                                      bf16* __restrict__ qb,
                                                      bf16* __restrict__ kb_,
                                                      bf16* __restrict__ vtb) {
  __shared__ __align__(16) unsigned char smem[16384];
  const int t = threadIdx.x, w = t >> 6, lane = t & 63;
  const int l4 = lane >> 4, l16 = lane & 15;
  const int bm = blockIdx.x % Mtiles, bn = blockIdx.x / Mtiles;
  const int wm = w >> 1, wn = w & 1;

  const char* aP[2];
  const char* bP[2];
#pragma unroll
  for (int p = 0; p < 2; ++p) {
    int g = p * 256 + t;
    aP[p] = (const char*)A + (size_t)(bm * 128 + (g >> 2)) * 4096 + (g & 3) * 16;
    bP[p] = (const char*)BT + (size_t)(bn * 128 + (g >> 2)) * 4096 + (g & 3) * 16;
  }
  const unsigned ldsW = w * 1024;

  const f32x4 fz = {0.f, 0.f, 0.f, 0.f};
  f32x4 acc[4][4];
#pragma unroll
  for (int i = 0; i < 4; ++i)
#pragma unroll
    for (int j = 0; j < 4; ++j) acc[i][j] = fz;

  const int arow = 64 * wm + l16, brow = 64 * wn + l16, kbyte = 16 * l4;

#pragma unroll 2
  for (int k0 = 0; k0 < 4096; k0 += 64) {
    gload16(aP[0] + k0, smem + ldsW);
    gload16(aP[1] + k0, smem + 4096 + ldsW);
    gload16(bP[0] + k0, smem + 8192 + ldsW);
    gload16(bP[1] + k0, smem + 12288 + ldsW);
    __syncthreads();
    bf16x8 af[4], bfr[4];
#pragma unroll
    for (int i = 0; i < 4; ++i)
      af[i] = *(const bf16x8*)(smem + (arow + 16 * i) * 64 + kbyte);
#pragma unroll
    for (int j = 0; j < 4; ++j)
      bfr[j] = *(const bf16x8*)(smem + 8192 + (brow + 16 * j) * 64 + kbyte);
#pragma unroll
    for (int i = 0; i < 4; ++i)
#pragma unroll
      for (int j = 0; j < 4; ++j)
        acc[i][j] = mfma16(af[i], bfr[j], acc[i][j]);
    __syncthreads();
  }

  const int r0 = bm * 128 + 64 * wm + 4 * l4;
  if (EPI == 1) {
#pragma unroll
    for (int j = 0; j < 4; ++j) {
      int col = bn * 128 + 64 * wn + 16 * j + l16;
#pragma unroll
      for (int i = 0; i < 4; ++i)
#pragma unroll
        for (int r = 0; r < 4; ++r)
          Cout[(size_t)(r0 + 16 * i + r) * 2048 + col] = acc[i][j][r];
    }
  } else {
    const int bq = bm >> 4;
#pragma unroll
    for (int j = 0; j < 4; ++j) {
      int col = bn * 128 + 64 * wn + 16 * j + l16;
      if (bn < 16) {        // Q -> [b][h][n][d]
        int hh = col >> 7, d = col & 127;
        bf16* dst = qb + (size_t)((bq * 16 + hh) * 2048) * 128 + d;
#pragma unroll
        for (int i = 0; i < 4; ++i)
#pragma unroll
          for (int r = 0; r < 4; ++r) {
            int n = (r0 + 16 * i + r) & 2047;
            dst[(size_t)n * 128] = (bf16)acc[i][j][r];
          }
      } else if (bn < 20) { // K -> [b][kv][n][d]
        int kv = (col >> 7) - 16, d = col & 127;
        bf16* dst = kb_ + (size_t)((bq * 4 + kv) * 2048) * 128 + d;
#pragma unroll
        for (int i = 0; i < 4; ++i)
#pragma unroll
          for (int r = 0; r < 4; ++r) {
            int n = (r0 + 16 * i + r) & 2047;
            dst[(size_t)n * 128] = (bf16)acc[i][j][r];
          }
      } else {              // V -> transposed [b][kv][d][n]
        int kv = (col >> 7) - 20, d = col & 127;
        bf16* dst = vtb + ((size_t)(bq * 4 + kv) * 128 + d) * 2048;
#pragma unroll
        for (int i = 0; i < 4; ++i)
#pragma unroll
          for (int r = 0; r < 4; ++r) {
            int n = (r0 + 16 * i + r) & 2047;
            dst[n] = (bf16)acc[i][j][r];
          }
      }
    }
  }
}

// ---------------- flash attention (GQA), 32x32 swapped, in-register softmax ----------------
// 4 waves x 32 q-rows = 128 q/block; KVBLK=64; dbuf K[64][128]+VT[128][64] bf16 (2x32KB).
// Swizzle: byte ^= (row&7)<<4 (staged via pre-swizzled global source, read with XOR).
__global__ __launch_bounds__(256, 2) void attn_kernel(const bf16* __restrict__ Q,
                                                      const bf16* __restrict__ K,
                                                      const bf16* __restrict__ VT,
                                                      bf16* __restrict__ AO) {
  __shared__ __align__(16) unsigned char smem[65536];
  const int t = threadIdx.x, w = t >> 6, lane = t & 63;
  const int q = lane & 31, hi = lane >> 5;
  const int pair = blockIdx.x >> 4;
  const int q00 = (blockIdx.x & 15) * 128 + w * 32;  // includes the wave offset
  const int b = pair >> 4, h = pair & 15, kvh = h >> 2;
  const float KS2 = 0.08838834764831845f * 1.4426950408889634f;  // scale * log2(e)

  // Q fragments: q-row = q00+q (lane-local), 8 d-chunks of 8 bf16
  bf16x8 qf[8];
  {
    const char* qbase = (const char*)Q +
        ((size_t)((b * 16 + h) * 2048 + q00 + q) * 128 + 8 * hi) * 2;
#pragma unroll
    for (int dk = 0; dk < 8; ++dk) qf[dk] = *(const bf16x8*)(qbase + dk * 32);
  }

  f32x16 acc[4];
#pragma unroll
  for (int dt = 0; dt < 4; ++dt)
#pragma unroll
    for (int r = 0; r < 16; ++r) acc[dt][r] = 0.0f;
  float mrun = -1e30f, lrun = 0.0f;

  const char* Kg = (const char*)K + (size_t)((b * 4 + kvh) * 2048) * 256;
  const char* Vg = (const char*)VT + (size_t)((b * 4 + kvh) * 128) * 4096;

  auto STAGE = [&](unsigned base, int itn) {
    const int kb = itn * 64;
#pragma unroll
    for (int p = 0; p < 4; ++p) {  // K tile [64][256B]
      int g = p * 256 + t;
      int row = g >> 4, cb = (g & 15) * 16;
      gload16(Kg + (size_t)(kb + row) * 256 + (cb ^ ((row & 7) << 4)),
              smem + base + p * 4096 + w * 1024);
    }
#pragma unroll
    for (int p = 0; p < 4; ++p) {  // VT tile [128][128B]
      int g = p * 256 + t;
      int row = g >> 3, cb = (g & 7) * 16;
      gload16(Vg + (size_t)row * 4096 + kb * 2 + (cb ^ ((row & 7) << 4)),
              smem + base + 16384 + p * 4096 + w * 1024);
    }
  };

  STAGE(0, 0);
  __syncthreads();

#pragma unroll 1
  for (int it = 0; it < 32; ++it) {
    const unsigned buf = (it & 1) ? 32768u : 0u;
    if (it < 31) STAGE(buf ^ 32768u, it + 1);  // prefetch overlaps compute

    // ---- S^T = K * Q^T : lane holds S[kv rows][q = lane&31] ----
    f32x16 s0, s1;
#pragma unroll
    for (int r = 0; r < 16; ++r) { s0[r] = 0.0f; s1[r] = 0.0f; }
    __builtin_amdgcn_s_setprio(1);
#pragma unroll
    for (int dk = 0; dk < 8; ++dk) {
      const int cb = dk * 32 + 16 * hi;
      bf16x8 k0 = *(const bf16x8*)(smem + buf + q * 256 + (cb ^ ((q & 7) << 4)));
      bf16x8 k1 = *(const bf16x8*)(smem + buf + (q + 32) * 256 + (cb ^ ((q & 7) << 4)));
      s0 = mfma32(k0, qf[dk], s0);
      s1 = mfma32(k1, qf[dk], s1);
    }
    __builtin_amdgcn_s_setprio(0);

    // ---- online softmax, fully in-register (one q per lane) ----
    float tm[16];
#pragma unroll
    for (int r = 0; r < 16; ++r) tm[r] = fmaxf(s0[r], s1[r]);
#pragma unroll
    for (int st = 8; st; st >>= 1)
#pragma unroll
      for (int r = 0; r < 8; ++r)
        if (r < st) tm[r] = fmaxf(tm[r], tm[r + st]);
    float mo = tm[0];
    mo = fmaxf(mo, __shfl_xor(mo, 32, 64));  // partner holds complementary kv set
    if (!__all((mo - mrun) * KS2 <= 8.0f)) {  // T13 defer-max
      float mn = fmaxf(mrun, mo);
      float al = __builtin_amdgcn_exp2f((mrun - mn) * KS2);
      lrun *= al;
#pragma unroll
      for (int dt = 0; dt < 4; ++dt)
#pragma unroll
        for (int r = 0; r < 16; ++r) acc[dt][r] *= al;
      mrun = mn;
    }
    const float c0 = KS2 * mrun;
    float p0[16], p1[16];
#pragma unroll
    for (int r = 0; r < 16; ++r) {
      p0[r] = __builtin_amdgcn_exp2f(s0[r] * KS2 - c0);
      p1[r] = __builtin_amdgcn_exp2f(s1[r] * KS2 - c0);
    }
    float ts[16];
#pragma unroll
    for (int r = 0; r < 16; ++r) ts[r] = p0[r] + p1[r];
#pragma unroll
    for (int st = 8; st; st >>= 1)
#pragma unroll
      for (int r = 0; r < 8; ++r)
        if (r < st) ts[r] += ts[r + st];
    float rs = ts[0];
    rs += __shfl_xor(rs, 32, 64);
    lrun += rs;

    // ---- P -> bf16 B-fragments via cvt_pk + permlane32_swap (T12) ----
    bf16x8 pa[4];
#pragma unroll
    for (int ks = 0; ks < 4; ++ks) {
      const int bs = (ks & 1) * 8;
      float* P = (ks >> 1) ? p1 : p0;
      u32 A0 = cvtpk(P[bs + 0], P[bs + 1]);
      u32 A1 = cvtpk(P[bs + 2], P[bs + 3]);
      u32 B0 = cvtpk(P[bs + 4], P[bs + 5]);
      u32 B1 = cvtpk(P[bs + 6], P[bs + 7]);
      plswap(A0, B0);
      plswap(A1, B1);
      union { u32 u[4]; bf16x8 v; } pu;
      pu.u[0] = A0; pu.u[1] = A1; pu.u[2] = B0; pu.u[3] = B1;
      pa[ks] = pu.v;
    }

    // ---- O^T += VT * P^T : lane holds O[d rows][q = lane&31] ----
    __builtin_amdgcn_s_setprio(1);
#pragma unroll
    for (int dt = 0; dt < 4; ++dt) {
      const int d = dt * 32 + q;
#pragma unroll
      for (int ks = 0; ks < 4; ++ks) {
        bf16x8 va = *(const bf16x8*)(smem + buf + 16384 + d * 128 +
                                     ((ks * 32 + 16 * hi) ^ ((d & 7) << 4)));
        acc[dt] = mfma32(va, pa[ks], acc[dt]);
      }
    }
    __builtin_amdgcn_s_setprio(0);
    __syncthreads();
  }

  // ---- epilogue: normalize + packed 8B stores (4 consecutive d per store) ----
  // NOTE: q00 already includes w*32 — do NOT add it again (R2 bug: stale rows -> absmax 5.2)
  const float inv = 1.0f / lrun;
  bf16* aorow = AO + (size_t)(b * 2048 + q00 + q) * 2048 + h * 128;
#pragma unroll
  for (int dt = 0; dt < 4; ++dt)
#pragma unroll
    for (int rq = 0; rq < 4; ++rq) {
      u32 w0 = cvtpk(acc[dt][rq * 4 + 0] * inv, acc[dt][rq * 4 + 1] * inv);
      u32 w1 = cvtpk(acc[dt][rq * 4 + 2] * inv, acc[dt][rq * 4 + 3] * inv);
      u32x2 pr; pr.x = w0; pr.y = w1;
      *(u32x2*)(aorow + dt * 32 + rq * 8 + 4 * hi) = pr;
    }
}

extern "C" void kernel_launch(void* const* d_in, const int* in_sizes, int n_in,
                              void* d_out, int out_size, void* d_ws, size_t ws_size,
                              hipStream_t stream) {
  const float* x = (const float*)d_in[0];
  const float* Wq = (const float*)d_in[1];
  const float* Wk = (const float*)d_in[2];
  const float* Wv = (const float*)d_in[3];
  const float* Wo = (const float*)d_in[4];

  char* ws = (char*)d_ws;
  bf16* xbf = (bf16*)(ws);                  // 16 MiB [4096][2048]; reused as AO
  bf16* WqkvT = (bf16*)(ws + 16777216);     // 12 MiB [3072][2048]
  bf16* WoT = (bf16*)(ws + 29360128);       //  8 MiB [2048][2048]
  bf16* Qbuf = (bf16*)(ws + 37748736);      // 16 MiB [b][h][n][128]
  bf16* Kbuf = (bf16*)(ws + 54525952);      //  4 MiB [b][kv][n][128]
  bf16* VTbuf = (bf16*)(ws + 58720256);     //  4 MiB [b][kv][128][n]

  cast_x_kernel<<<4096, 256, 0, stream>>>(x, xbf, 1048576);
  transpose_cast_kernel<<<1024, 256, 0, stream>>>(Wq, WqkvT, 2048, 2048);
  transpose_cast_kernel<<<256, 256, 0, stream>>>(Wk, WqkvT + (size_t)2048 * 2048, 2048, 512);
  transpose_cast_kernel<<<256, 256, 0, stream>>>(Wv, WqkvT + (size_t)2560 * 2048, 2048, 512);
  transpose_cast_kernel<<<1024, 256, 0, stream>>>(Wo, WoT, 2048, 2048);

  gemm_bt_kernel<0><<<768, 256, 0, stream>>>(xbf, WqkvT, nullptr, 32, Qbuf, Kbuf, VTbuf);
  attn_kernel<<<512, 256, 0, stream>>>(Qbuf, Kbuf, VTbuf, xbf);
  gemm_bt_kernel<1><<<512, 256, 0, stream>>>(xbf, WoT, (float*)d_out, 32, nullptr, nullptr, nullptr);
}

// Round 5
// 213.404 us; speedup vs baseline: 1.6304x; 1.0144x over previous
//
#include <hip/hip_runtime.h>
#include <hip/hip_bf16.h>
#include <cstdint>
#include <cstddef>

typedef __bf16 bf16;
typedef __attribute__((ext_vector_type(8))) __bf16 bf16x8;
typedef __attribute__((ext_vector_type(4))) float f32x4;
typedef __attribute__((ext_vector_type(16))) float f32x16;
typedef unsigned int u32;
typedef __attribute__((ext_vector_type(2))) unsigned int u32x2;

#define DEVINL __device__ __forceinline__

DEVINL void gload16(const void* g, void* l) {
  __builtin_amdgcn_global_load_lds(
      (const __attribute__((address_space(1))) void*)g,
      (__attribute__((address_space(3))) void*)l, 16, 0, 0);
}

DEVINL f32x4 mfma16(bf16x8 a, bf16x8 b, f32x4 c) {
  return __builtin_amdgcn_mfma_f32_16x16x32_bf16(a, b, c, 0, 0, 0);
}
DEVINL f32x16 mfma32(bf16x8 a, bf16x8 b, f32x16 c) {
  return __builtin_amdgcn_mfma_f32_32x32x16_bf16(a, b, c, 0, 0, 0);
}
DEVINL u32 cvtpk(float lo, float hi) {
  u32 r;
  asm("v_cvt_pk_bf16_f32 %0, %1, %2" : "=v"(r) : "v"(lo), "v"(hi));
  return r;
}
DEVINL void plswap(u32& a, u32& b) {
  asm("v_permlane32_swap_b32 %0, %1" : "+v"(a), "+v"(b));
}

// ---------------- cast x fp32 -> bf16, 8 elem/thread ----------------
__global__ __launch_bounds__(256) void cast_x_kernel(const float* __restrict__ x,
                                                     bf16* __restrict__ o, int n8) {
  int i = blockIdx.x * 256 + threadIdx.x;
  if (i >= n8) return;
  f32x4 a = ((const f32x4*)x)[2 * i];
  f32x4 b = ((const f32x4*)x)[2 * i + 1];
  bf16x8 v;
#pragma unroll
  for (int k = 0; k < 4; ++k) { v[k] = (bf16)a[k]; v[4 + k] = (bf16)b[k]; }
  ((bf16x8*)o)[i] = v;
}

// ---------- transpose+cast: src fp32 [K][N] -> dst bf16 [N][K] (K stride 2048) ----------
__global__ __launch_bounds__(256) void transpose_cast_kernel(const float* __restrict__ src,
                                                             bf16* __restrict__ dst,
                                                             int K, int N) {
  __shared__ float tile[64][65];
  int nt = N >> 6;
  int n0 = (blockIdx.x % nt) << 6;
  int k0 = (blockIdx.x / nt) << 6;
  int c = threadIdx.x & 63, rb = threadIdx.x >> 6;
#pragma unroll
  for (int rr = 0; rr < 16; ++rr) {
    int row = rr * 4 + rb;
    tile[row][c] = src[(size_t)(k0 + row) * N + n0 + c];
  }
  __syncthreads();
#pragma unroll
  for (int rr = 0; rr < 16; ++rr) {
    int nrow = rr * 4 + rb;
    dst[(size_t)(n0 + nrow) * K + k0 + c] = (bf16)tile[c][nrow];
  }
}

// ---------------- GEMM: C[M][N] = A[M][2048] * BT[N][2048]^T ----------------
// 128x128 tile, 4 waves (2x2), BK=32, T3-minimum double-buffer:
// STAGE(next) -> compute(cur) -> ONE barrier/iter (loads covered by compute).
template <int EPI>
__global__ __launch_bounds__(256) void gemm_bt_kernel(const bf16* __restrict__ A,
                                                      const bf16* __restrict__ BT,
                                                      float* __restrict__ Cout,
                                                      int Mtiles,
                                                      bf16* __restrict__ qb,
                                                      bf16* __restrict__ kb_,
                                                      bf16* __restrict__ vtb) {
  __shared__ __align__(16) unsigned char smem[32768];  // buf*16384: A[0,8K) B[8K,16K)
  const int t = threadIdx.x, w = t >> 6, lane = t & 63;
  const int l4 = lane >> 4, l16 = lane & 15;
  const int bm = blockIdx.x % Mtiles, bn = blockIdx.x / Mtiles;
  const int wm = w >> 1, wn = w & 1;

  const char* aP[2];
  const char* bP[2];
#pragma unroll
  for (int p = 0; p < 2; ++p) {
    int g = p * 256 + t;
    aP[p] = (const char*)A + (size_t)(bm * 128 + (g >> 2)) * 4096 + (g & 3) * 16;
    bP[p] = (const char*)BT + (size_t)(bn * 128 + (g >> 2)) * 4096 + (g & 3) * 16;
  }
  const unsigned ldsW = w * 1024;

  auto STAGE = [&](unsigned buf, int k0) {
    gload16(aP[0] + k0, smem + buf * 16384 + ldsW);
    gload16(aP[1] + k0, smem + buf * 16384 + 4096 + ldsW);
    gload16(bP[0] + k0, smem + buf * 16384 + 8192 + ldsW);
    gload16(bP[1] + k0, smem + buf * 16384 + 12288 + ldsW);
  };

  const f32x4 fz = {0.f, 0.f, 0.f, 0.f};
  f32x4 acc[4][4];
#pragma unroll
  for (int i = 0; i < 4; ++i)
#pragma unroll
    for (int j = 0; j < 4; ++j) acc[i][j] = fz;

  const int arow = 64 * wm + l16, brow = 64 * wn + l16, kbyte = 16 * l4;

  STAGE(0, 0);
  __syncthreads();

#pragma unroll 2
  for (int tt = 0; tt < 64; ++tt) {  // 64 K-steps of 32 bf16 (64 bytes)
    const unsigned buf = tt & 1;
    if (tt < 63) STAGE(buf ^ 1u, (tt + 1) * 64);
    bf16x8 af[4], bfr[4];
#pragma unroll
    for (int i = 0; i < 4; ++i)
      af[i] = *(const bf16x8*)(smem + buf * 16384 + (arow + 16 * i) * 64 + kbyte);
#pragma unroll
    for (int j = 0; j < 4; ++j)
      bfr[j] = *(const bf16x8*)(smem + buf * 16384 + 8192 + (brow + 16 * j) * 64 + kbyte);
#pragma unroll
    for (int i = 0; i < 4; ++i)
#pragma unroll
      for (int j = 0; j < 4; ++j)
        acc[i][j] = mfma16(af[i], bfr[j], acc[i][j]);
    __syncthreads();  // drains stage loads (covered) + read/write slot handoff
  }

  const int r0 = bm * 128 + 64 * wm + 4 * l4;
  if (EPI == 1) {
#pragma unroll
    for (int j = 0; j < 4; ++j) {
      int col = bn * 128 + 64 * wn + 16 * j + l16;
#pragma unroll
      for (int i = 0; i < 4; ++i)
#pragma unroll
        for (int r = 0; r < 4; ++r)
          Cout[(size_t)(r0 + 16 * i + r) * 2048 + col] = acc[i][j][r];
    }
  } else {
    const int bq = bm >> 4;
#pragma unroll
    for (int j = 0; j < 4; ++j) {
      int col = bn * 128 + 64 * wn + 16 * j + l16;
      if (bn < 16) {        // Q -> [b][h][n][d]
        int hh = col >> 7, d = col & 127;
        bf16* dst = qb + (size_t)((bq * 16 + hh) * 2048) * 128 + d;
#pragma unroll
        for (int i = 0; i < 4; ++i)
#pragma unroll
          for (int r = 0; r < 4; ++r) {
            int n = (r0 + 16 * i + r) & 2047;
            dst[(size_t)n * 128] = (bf16)acc[i][j][r];
          }
      } else if (bn < 20) { // K -> [b][kv][n][d]
        int kv = (col >> 7) - 16, d = col & 127;
        bf16* dst = kb_ + (size_t)((bq * 4 + kv) * 2048) * 128 + d;
#pragma unroll
        for (int i = 0; i < 4; ++i)
#pragma unroll
          for (int r = 0; r < 4; ++r) {
            int n = (r0 + 16 * i + r) & 2047;
            dst[(size_t)n * 128] = (bf16)acc[i][j][r];
          }
      } else {              // V -> transposed [b][kv][d][n]
        int kv = (col >> 7) - 20, d = col & 127;
        bf16* dst = vtb + ((size_t)(bq * 4 + kv) * 128 + d) * 2048;
#pragma unroll
        for (int i = 0; i < 4; ++i)
#pragma unroll
          for (int r = 0; r < 4; ++r) {
            int n = (r0 + 16 * i + r) & 2047;
            dst[n] = (bf16)acc[i][j][r];
          }
      }
    }
  }
}

// ---------------- flash attention (GQA), 32x32 swapped, software-pipelined ----------------
// 4 waves x 32 q; KVBLK=64. LDS 64KB: K slots @0/@16K (dbuf, staged 1 ahead),
// VT slots @32K/@48K (dbuf, staged SAME iter, consumed next iter).
// Iter i: STAGE(K_{i+1}, VT_i); S-MFMA(i); FINISH(i-1){softmax+pack+PV}; barrier.
// FINISH(i-1) is independent of S-MFMA(i) -> VALU overlaps the MFMA pipe.
__global__ __launch_bounds__(256, 2) void attn_kernel(const bf16* __restrict__ Q,
                                                      const bf16* __restrict__ K,
                                                      const bf16* __restrict__ VT,
                                                      bf16* __restrict__ AO) {
  __shared__ __align__(16) unsigned char smem[65536];
  const int t = threadIdx.x, w = t >> 6, lane = t & 63;
  const int q = lane & 31, hi = lane >> 5;
  const int pair = blockIdx.x >> 4;
  const int q00 = (blockIdx.x & 15) * 128 + w * 32;  // includes wave offset
  const int b = pair >> 4, h = pair & 15, kvh = h >> 2;
  const float KS2 = 0.08838834764831845f * 1.4426950408889634f;  // scale * log2(e)

  bf16x8 qf[8];
  {
    const char* qbase = (const char*)Q +
        ((size_t)((b * 16 + h) * 2048 + q00 + q) * 128 + 8 * hi) * 2;
#pragma unroll
    for (int dk = 0; dk < 8; ++dk) qf[dk] = *(const bf16x8*)(qbase + dk * 32);
  }

  f32x16 acc[4];
#pragma unroll
  for (int dt = 0; dt < 4; ++dt)
#pragma unroll
    for (int r = 0; r < 16; ++r) acc[dt][r] = 0.0f;
  float mrun = -1e30f, lrun = 0.0f;

  const char* Kg = (const char*)K + (size_t)((b * 4 + kvh) * 2048) * 256;
  const char* Vg = (const char*)VT + (size_t)((b * 4 + kvh) * 128) * 4096;

  auto STAGE_K = [&](int itn) {  // K(itn) -> slot itn&1 (@0 / @16K)
    const unsigned base = (unsigned)(itn & 1) * 16384u;
    const int kb = itn * 64;
#pragma unroll
    for (int p = 0; p < 4; ++p) {
      int g = p * 256 + t;
      int row = g >> 4, cb = (g & 15) * 16;
      gload16(Kg + (size_t)(kb + row) * 256 + (cb ^ ((row & 7) << 4)),
              smem + base + p * 4096 + w * 1024);
    }
  };
  auto STAGE_V = [&](int itn) {  // VT(itn) -> slot itn&1 (@32K / @48K)
    const unsigned base = 32768u + (unsigned)(itn & 1) * 16384u;
    const int kb = itn * 64;
#pragma unroll
    for (int p = 0; p < 4; ++p) {
      int g = p * 256 + t;
      int row = g >> 3, cb = (g & 7) * 16;
      gload16(Vg + (size_t)row * 4096 + kb * 2 + (cb ^ ((row & 7) << 4)),
              smem + base + p * 4096 + w * 1024);  // FIX: was base+16384+... (R4 NaN: slot-0 never written, slot-1 OOB)
    }
  };

  auto SMFMA = [&](int itn, f32x16& s0, f32x16& s1) {
    const unsigned base = (unsigned)(itn & 1) * 16384u;
#pragma unroll
    for (int r = 0; r < 16; ++r) { s0[r] = 0.0f; s1[r] = 0.0f; }
    __builtin_amdgcn_s_setprio(1);
#pragma unroll
    for (int dk = 0; dk < 8; ++dk) {
      const int cb = dk * 32 + 16 * hi;
      bf16x8 k0 = *(const bf16x8*)(smem + base + q * 256 + (cb ^ ((q & 7) << 4)));
      bf16x8 k1 = *(const bf16x8*)(smem + base + (q + 32) * 256 + (cb ^ ((q & 7) << 4)));
      s0 = mfma32(k0, qf[dk], s0);
      s1 = mfma32(k1, qf[dk], s1);
    }
    __builtin_amdgcn_s_setprio(0);
  };

  auto FINISH = [&](int itn, f32x16& s0, f32x16& s1) {
    float tm[16];
#pragma unroll
    for (int r = 0; r < 16; ++r) tm[r] = fmaxf(s0[r], s1[r]);
#pragma unroll
    for (int st = 8; st; st >>= 1)
#pragma unroll
      for (int r = 0; r < 8; ++r)
        if (r < st) tm[r] = fmaxf(tm[r], tm[r + st]);
    float mo = tm[0];
    mo = fmaxf(mo, __shfl_xor(mo, 32, 64));
    if (!__all((mo - mrun) * KS2 <= 8.0f)) {  // T13 defer-max
      float mn = fmaxf(mrun, mo);
      float al = __builtin_amdgcn_exp2f((mrun - mn) * KS2);
      lrun *= al;
#pragma unroll
      for (int dt = 0; dt < 4; ++dt)
#pragma unroll
        for (int r = 0; r < 16; ++r) acc[dt][r] *= al;
      mrun = mn;
    }
    const float c0 = KS2 * mrun;
    float p0[16], p1[16];
#pragma unroll
    for (int r = 0; r < 16; ++r) {
      p0[r] = __builtin_amdgcn_exp2f(s0[r] * KS2 - c0);
      p1[r] = __builtin_amdgcn_exp2f(s1[r] * KS2 - c0);
    }
    float ts[16];
#pragma unroll
    for (int r = 0; r < 16; ++r) ts[r] = p0[r] + p1[r];
#pragma unroll
    for (int st = 8; st; st >>= 1)
#pragma unroll
      for (int r = 0; r < 8; ++r)
        if (r < st) ts[r] += ts[r + st];
    float rs = ts[0];
    rs += __shfl_xor(rs, 32, 64);
    lrun += rs;

    bf16x8 pa[4];
#pragma unroll
    for (int ks = 0; ks < 4; ++ks) {
      const int bs = (ks & 1) * 8;
      float* P = (ks >> 1) ? p1 : p0;
      u32 A0 = cvtpk(P[bs + 0], P[bs + 1]);
      u32 A1 = cvtpk(P[bs + 2], P[bs + 3]);
      u32 B0 = cvtpk(P[bs + 4], P[bs + 5]);
      u32 B1 = cvtpk(P[bs + 6], P[bs + 7]);
      plswap(A0, B0);
      plswap(A1, B1);
      union { u32 u[4]; bf16x8 v; } pu;
      pu.u[0] = A0; pu.u[1] = A1; pu.u[2] = B0; pu.u[3] = B1;
      pa[ks] = pu.v;
    }

    const unsigned vbase = 32768u + (unsigned)(itn & 1) * 16384u;
    __builtin_amdgcn_s_setprio(1);
#pragma unroll
    for (int dt = 0; dt < 4; ++dt) {
      const int d = dt * 32 + q;
#pragma unroll
      for (int ks = 0; ks < 4; ++ks) {
        bf16x8 va = *(const bf16x8*)(smem + vbase + d * 128 +
                                     ((ks * 32 + 16 * hi) ^ ((d & 7) << 4)));
        acc[dt] = mfma32(va, pa[ks], acc[dt]);
      }
    }
    __builtin_amdgcn_s_setprio(0);
  };

  // ---- pipeline ----
  f32x16 sA0, sA1, sB0, sB1;
  STAGE_K(0);
  __syncthreads();

  // iter 0: no FINISH yet
  STAGE_K(1);
  STAGE_V(0);
  SMFMA(0, sA0, sA1);
  __syncthreads();

#pragma unroll 1
  for (int i = 1; i < 31; i += 2) {
    STAGE_K(i + 1);
    STAGE_V(i);
    SMFMA(i, sB0, sB1);
    FINISH(i - 1, sA0, sA1);
    __syncthreads();
    STAGE_K(i + 2);
    STAGE_V(i + 1);
    SMFMA(i + 1, sA0, sA1);
    FINISH(i, sB0, sB1);
    __syncthreads();
  }

  // iter 31 (K(31) staged at i=29 second half)
  STAGE_V(31);
  SMFMA(31, sB0, sB1);
  FINISH(30, sA0, sA1);
  __syncthreads();
  FINISH(31, sB0, sB1);

  // ---- epilogue: normalize + packed 8B stores ----
  const float inv = 1.0f / lrun;
  bf16* aorow = AO + (size_t)(b * 2048 + q00 + q) * 2048 + h * 128;
#pragma unroll
  for (int dt = 0; dt < 4; ++dt)
#pragma unroll
    for (int rq = 0; rq < 4; ++rq) {
      u32 w0 = cvtpk(acc[dt][rq * 4 + 0] * inv, acc[dt][rq * 4 + 1] * inv);
      u32 w1 = cvtpk(acc[dt][rq * 4 + 2] * inv, acc[dt][rq * 4 + 3] * inv);
      u32x2 pr; pr.x = w0; pr.y = w1;
      *(u32x2*)(aorow + dt * 32 + rq * 8 + 4 * hi) = pr;
    }
}

extern "C" void kernel_launch(void* const* d_in, const int* in_sizes, int n_in,
                              void* d_out, int out_size, void* d_ws, size_t ws_size,
                              hipStream_t stream) {
  const float* x = (const float*)d_in[0];
  const float* Wq = (const float*)d_in[1];
  const float* Wk = (const float*)d_in[2];
  const float* Wv = (const float*)d_in[3];
  const float* Wo = (const float*)d_in[4];

  char* ws = (char*)d_ws;
  bf16* xbf = (bf16*)(ws);                  // 16 MiB [4096][2048]; reused as AO
  bf16* WqkvT = (bf16*)(ws + 16777216);     // 12 MiB [3072][2048]
  bf16* WoT = (bf16*)(ws + 29360128);       //  8 MiB [2048][2048]
  bf16* Qbuf = (bf16*)(ws + 37748736);      // 16 MiB [b][h][n][128]
  bf16* Kbuf = (bf16*)(ws + 54525952);      //  4 MiB [b][kv][n][128]
  bf16* VTbuf = (bf16*)(ws + 58720256);     //  4 MiB [b][kv][128][n]

  cast_x_kernel<<<4096, 256, 0, stream>>>(x, xbf, 1048576);
  transpose_cast_kernel<<<1024, 256, 0, stream>>>(Wq, WqkvT, 2048, 2048);
  transpose_cast_kernel<<<256, 256, 0, stream>>>(Wk, WqkvT + (size_t)2048 * 2048, 2048, 512);
  transpose_cast_kernel<<<256, 256, 0, stream>>>(Wv, WqkvT + (size_t)2560 * 2048, 2048, 512);
  transpose_cast_kernel<<<1024, 256, 0, stream>>>(Wo, WoT, 2048, 2048);

  gemm_bt_kernel<0><<<768, 256, 0, stream>>>(xbf, WqkvT, nullptr, 32, Qbuf, Kbuf, VTbuf);
  attn_kernel<<<512, 256, 0, stream>>>(Qbuf, Kbuf, VTbuf, xbf);
  gemm_bt_kernel<1><<<512, 256, 0, stream>>>(xbf, WoT, (float*)d_out, 32, nullptr, nullptr, nullptr);
}